// Round 3
// baseline (6315.433 us; speedup 1.0000x reference)
//
#include <hip/hip_runtime.h>
#include <math.h>

#define NLAY   6
#define Hd     256
#define DINv   512
#define NHEADS 8
#define CONVDv 640
#define PROJv  1160   // 2*DIN + 2*N + HEADS
#define ZW     656    // zsmall row: z 512 | B 64 | C 64 | dt 8 | pad 8
#define NTOK   65536
#define NCH    1024   // 64-token chunks

typedef __attribute__((ext_vector_type(8))) short bf16x8;
typedef __attribute__((ext_vector_type(4))) float f32x4;
typedef unsigned short u16;

__device__ __forceinline__ float siluf(float v) {
    // fast silu: v * rcp(1 + exp(-v)); result is bf16-rounded downstream.
    return v * __builtin_amdgcn_rcpf(1.0f + __expf(-v));
}
__device__ __forceinline__ float bflo(unsigned u) { return __uint_as_float(u << 16); }
__device__ __forceinline__ float bfhi(unsigned u) { return __uint_as_float(u & 0xffff0000u); }
__device__ __forceinline__ u16 f2b(float f) {  // RNE fp32->bf16
    unsigned u = __float_as_uint(f);
    return (u16)((u + 0x7fffu + ((u >> 16) & 1u)) >> 16);
}
__device__ __forceinline__ float b2f(u16 s) { return __uint_as_float(((unsigned)s) << 16); }

__device__ __forceinline__ void gl_lds16(const void* g, void* l) {
    __builtin_amdgcn_global_load_lds((const __attribute__((address_space(1))) unsigned int*)g,
                                     (__attribute__((address_space(3))) unsigned int*)l, 16, 0, 0);
}

// ---------- prep: Win -> bf16 hi/lo, fragment order [li][j(74)][kk(8)][quad(4)][col(16)][e(8)] ----------
// [quad][col] order => a wave's ds_read_b128 of one kk-block is byte-linear in lane
// (lane*16) => conflict-free.
__global__ __launch_bounds__(512)
void kprep_win(const float* __restrict__ tW, const float* __restrict__ bW,
               u16* __restrict__ Whi, u16* __restrict__ Wlo)
{
    const int li = blockIdx.y, j = blockIdx.x;    // j 0..73
    const int t  = threadIdx.x;
    const int kk = t >> 6, col = (t >> 2) & 15, quad = t & 3;
    const float* W = (li < 6) ? (tW + (size_t)li * Hd * PROJv)
                              : (bW + (size_t)(li - 6) * Hd * PROJv);
    const int fullcol = 16 * j + col;
    const size_t ob = ((size_t)li * 74 + j) * 4096 + kk * 512 + quad * 128 + col * 8;
#pragma unroll
    for (int e = 0; e < 8; e++) {
        const int k = kk * 32 + quad * 8 + e;
        const float v = (fullcol < PROJv) ? W[(size_t)k * PROJv + fullcol] : 0.f;
        const u16 hi = f2b(v);
        Whi[ob + e] = hi;
        Wlo[ob + e] = f2b(v - b2f(hi));
    }
}

// ---------- prep: Wout*gn -> bf16 hi/lo, fragment order [li][j(16)][kk(16)][quad(4)][col(16)][e(8)] ----------
__global__ __launch_bounds__(512)
void kprep_wout(const float* __restrict__ tW, const float* __restrict__ tg,
                const float* __restrict__ bW, const float* __restrict__ bg,
                u16* __restrict__ Whi, u16* __restrict__ Wlo)
{
    const int li = blockIdx.y, j = blockIdx.x;    // j 0..15
    const int t  = threadIdx.x;
    const int kk = t >> 5, col = (t >> 1) & 15, qh = t & 1;
    const float* W = (li < 6) ? tW + (size_t)li * DINv * Hd : bW + (size_t)(li - 6) * DINv * Hd;
    const float* g = (li < 6) ? tg + li * DINv : bg + (li - 6) * DINv;
    const int fullcol = 16 * j + col;
#pragma unroll
    for (int q = 0; q < 2; q++) {
        const int quad = qh * 2 + q;
        const size_t ob = ((size_t)li * 16 + j) * 8192 + kk * 512 + quad * 128 + col * 8;
#pragma unroll
        for (int e = 0; e < 8; e++) {
            const int k = kk * 32 + quad * 8 + e;
            const float v = W[(size_t)k * Hd + fullcol] * g[k];
            const u16 hi = f2b(v);
            Whi[ob + e] = hi;
            Wlo[ob + e] = f2b(v - b2f(hi));
        }
    }
}

// ---------- K1: rmsnorm(x) @ Win. z/B/C/dt -> zs rows; xs -> xrawT[p][t]; halo dup -> bnd ----------
__global__ __launch_bounds__(512, 4)
void k1_mfma(const float* __restrict__ src, u16* __restrict__ zs,
             u16* __restrict__ xrawT, u16* __restrict__ bnd,
             const float* __restrict__ nw,
             const u16* __restrict__ Whi, const u16* __restrict__ Wlo)
{
    __shared__ __align__(16) char smem[67584];    // union: sA (66KB) then sW dbuf (64KB)
    u16* sAh = (u16*)smem;                        // 64*264
    u16* sAl = sAh + 64 * 264;
    const int tid = threadIdx.x;
    const int cb  = blockIdx.x;
    const int R0  = cb * 64;

    { // phase A: load 64x256 fp32, rmsnorm, hi/lo -> LDS
        const int tok = tid >> 3, l8 = tid & 7;
        const float* xr = src + ((size_t)(R0 + tok)) * Hd + l8 * 32;
        float vv[32];
#pragma unroll
        for (int q = 0; q < 8; q++) {
            float4 v = ((const float4*)xr)[q];
            vv[4*q] = v.x; vv[4*q+1] = v.y; vv[4*q+2] = v.z; vv[4*q+3] = v.w;
        }
        float ss = 0.f;
#pragma unroll
        for (int j = 0; j < 32; j++) ss += vv[j] * vv[j];
#pragma unroll
        for (int m = 4; m >= 1; m >>= 1) ss += __shfl_xor(ss, m, 8);
        const float rstd = rsqrtf(ss * (1.0f / Hd) + 1e-6f);
        const float* nr = nw + l8 * 32;
        u16* dh = sAh + tok * 264 + l8 * 32;
        u16* dl = sAl + tok * 264 + l8 * 32;
#pragma unroll
        for (int j = 0; j < 32; j++) {
            const float val = vv[j] * rstd * nr[j];
            const u16 hi = f2b(val);
            dh[j] = hi;
            dl[j] = f2b(val - b2f(hi));
        }
    }
    __syncthreads();

    const int lane = tid & 63, wave = tid >> 6;
    const int rh = wave >> 1, cw = wave & 1;
    const int quad = lane >> 4, m16 = lane & 15;

    bf16x8 ah[8], al[8];
    {
        const u16* ph = sAh + (rh * 16 + m16) * 264 + quad * 8;
        const u16* pl = sAl + (rh * 16 + m16) * 264 + quad * 8;
#pragma unroll
        for (int kk = 0; kk < 8; kk++) {
            ah[kk] = *(const bf16x8*)(ph + kk * 32);
            al[kk] = *(const bf16x8*)(pl + kk * 32);
        }
    }
    __syncthreads();   // all frag reads done before sW overlays sA

    u16* sW = (u16*)smem;  // 2 bufs x 16384 u16

#define K1_STAGE(p, buf)                                                          \
    {                                                                             \
        const int obase = wave * 4096;                                            \
        _Pragma("unroll")                                                         \
        for (int i = 0; i < 4; i++) {                                             \
            const int o = obase + i * 1024;                                       \
            const int chunk = o >> 13, t2 = chunk >> 1, hl = chunk & 1;           \
            const int within = o & 8191;                                          \
            const u16* sbase = (hl ? Wlo : Whi) + (size_t)(2 * (p) + t2) * 4096;  \
            gl_lds16((const char*)sbase + within + lane * 16,                     \
                     (char*)sW + (buf) * 32768 + o);                              \
        }                                                                         \
    }

    K1_STAGE(0, 0);
    __syncthreads();

    for (int p = 0; p < 37; p++) {
        if (p < 36) K1_STAGE(p + 1, (p + 1) & 1);
        const int j = 2 * p + cw;
        const u16* tb = sW + (p & 1) * 16384 + cw * 8192 + lane * 8;   // linear in lane
        f32x4 acc = (f32x4){0.f, 0.f, 0.f, 0.f};
#pragma unroll
        for (int kk = 0; kk < 8; kk++) {
            bf16x8 bh = *(const bf16x8*)(tb + kk * 512);
            bf16x8 bl = *(const bf16x8*)(tb + 4096 + kk * 512);
            acc = __builtin_amdgcn_mfma_f32_16x16x32_bf16(ah[kk], bh, acc, 0, 0, 0);
            acc = __builtin_amdgcn_mfma_f32_16x16x32_bf16(al[kk], bh, acc, 0, 0, 0);
            acc = __builtin_amdgcn_mfma_f32_16x16x32_bf16(ah[kk], bl, acc, 0, 0, 0);
        }
        const int fullcol = 16 * j + m16;
        if (j < 32) {                         // z columns
            u16* zr = zs + (size_t)(R0 + rh * 16 + quad * 4) * ZW + fullcol;
#pragma unroll
            for (int i = 0; i < 4; i++) zr[(size_t)i * ZW] = f2b(acc[i]);
        } else if (j < 64) {                  // xs -> xrawT [ch][t], packed 4 u16
            const int ch = fullcol - 512;
            uint2 v;
            v.x = (unsigned)f2b(acc[0]) | ((unsigned)f2b(acc[1]) << 16);
            v.y = (unsigned)f2b(acc[2]) | ((unsigned)f2b(acc[3]) << 16);
            *(uint2*)(xrawT + ((size_t)cb * 512 + ch) * 64 + rh * 16 + quad * 4) = v;
            if (rh == 3 && quad == 3) {       // rows 61..63 halo dup
#pragma unroll
                for (int i = 1; i < 4; i++)
                    bnd[((size_t)cb * 3 + (i - 1)) * 640 + ch] = f2b(acc[i]);
            }
        } else if (j < 73) {                  // B/C/dt columns (zs col = fullcol-512)
            const int zc = fullcol - 512;
            u16* zr = zs + (size_t)(R0 + rh * 16 + quad * 4) * ZW + zc;
#pragma unroll
            for (int i = 0; i < 4; i++) zr[(size_t)i * ZW] = f2b(acc[i]);
            if (j < 72 && rh == 3 && quad == 3) {
#pragma unroll
                for (int i = 1; i < 4; i++)
                    bnd[((size_t)cb * 3 + (i - 1)) * 640 + zc] = f2b(acc[i]);
            }
        }
        __syncthreads();
    }
#undef K1_STAGE
}

// ---------- K2a: conv4+silu (FIR -> fully t-parallel) + softplus/logdA ----------
__device__ __forceinline__ void conv32_rmw(u16* xp, float w0, float w1, float w2, float w3,
                                           float bias, float h3, float h2, float h1)
{
    uint4 va = ((const uint4*)xp)[0], vb = ((const uint4*)xp)[1],
          vc = ((const uint4*)xp)[2], vd = ((const uint4*)xp)[3];
    unsigned uu[16] = {va.x, va.y, va.z, va.w, vb.x, vb.y, vb.z, vb.w,
                       vc.x, vc.y, vc.z, vc.w, vd.x, vd.y, vd.z, vd.w};
    unsigned ou[16];
#pragma unroll
    for (int k = 0; k < 16; k++) {
        const float x0 = bflo(uu[k]);
        const u16 o0 = f2b(siluf(bias + w0*h3 + w1*h2 + w2*h1 + w3*x0));
        h3 = h2; h2 = h1; h1 = x0;
        const float x1 = bfhi(uu[k]);
        const u16 o1 = f2b(siluf(bias + w0*h3 + w1*h2 + w2*h1 + w3*x1));
        h3 = h2; h2 = h1; h1 = x1;
        ou[k] = (unsigned)o0 | ((unsigned)o1 << 16);
    }
    ((uint4*)xp)[0] = make_uint4(ou[0],  ou[1],  ou[2],  ou[3]);
    ((uint4*)xp)[1] = make_uint4(ou[4],  ou[5],  ou[6],  ou[7]);
    ((uint4*)xp)[2] = make_uint4(ou[8],  ou[9],  ou[10], ou[11]);
    ((uint4*)xp)[3] = make_uint4(ou[12], ou[13], ou[14], ou[15]);
}

__global__ __launch_bounds__(256, 4)
void k2a_conv(u16* __restrict__ zs, u16* __restrict__ xrawT,
              float* __restrict__ spb, const u16* __restrict__ bnd,
              const float* __restrict__ cwp, const float* __restrict__ cbp,
              const float* __restrict__ dtbp, const float* __restrict__ alogp, int L)
{
    __shared__ __align__(16) u16 sBC[64][128];   // 16 KB: pre-conv B/C, [t][ch']
    const int tid = threadIdx.x;
    const int cb  = blockIdx.x;
    const size_t row0 = (size_t)cb * 64;
    const bool atStart = (((int)(row0 % (size_t)L)) == 0);
    const int lane = tid & 63, wave = tid >> 6;

    // --- issue async stage of pre-conv B/C (zs cols 512..639) -> LDS ---
#pragma unroll
    for (int j = 0; j < 4; j++) {
        const int t0 = wave * 16 + j * 4;        // wave-uniform LDS dest; per-lane src
        gl_lds16(zs + (row0 + t0 + (lane >> 4)) * ZW + 512 + (lane & 15) * 8,
                 (char*)sBC + t0 * 256);
    }

    // --- xs phase 1: upper half-rows t[32..64), halo x[29..31] read pre-conv ---
#pragma unroll
    for (int cc = 0; cc < 2; cc++) {
        const int ch = tid + cc * 256;
        const float w0 = cwp[0*CONVDv + ch], w1 = cwp[1*CONVDv + ch],
                    w2 = cwp[2*CONVDv + ch], w3 = cwp[3*CONVDv + ch];
        u16* xp = xrawT + ((size_t)cb * 512 + ch) * 64 + 32;
        const uint2 hv = *(const uint2*)(xp - 4);          // x[28..31]
        conv32_rmw(xp, w0, w1, w2, w3, cbp[ch], bfhi(hv.x), bflo(hv.y), bfhi(hv.y));
    }

    // --- dt: pointwise softplus + log dA, one token-row per thread ---
    if (tid < 64) {
        const int t = tid;
        const uint4 dv = *(const uint4*)(zs + (row0 + t) * ZW + 640);   // heads 0..7
        const unsigned uu[4] = {dv.x, dv.y, dv.z, dv.w};
        float sp[8], ld[8];
#pragma unroll
        for (int h = 0; h < 8; h++) {
            const float d = ((h & 1) ? bfhi(uu[h >> 1]) : bflo(uu[h >> 1])) + dtbp[h];
            const float s = (d > 20.f) ? d : __logf(1.f + __expf(d));
            sp[h] = s;
            ld[h] = -__expf(alogp[h]) * s;
        }
        float* ob = spb + (row0 + t) * 24;
        *(float4*)(ob)      = make_float4(sp[0], sp[1], sp[2], sp[3]);
        *(float4*)(ob + 4)  = make_float4(sp[4], sp[5], sp[6], sp[7]);
        *(float4*)(ob + 8)  = make_float4(ld[0], ld[1], ld[2], ld[3]);
        *(float4*)(ob + 12) = make_float4(ld[4], ld[5], ld[6], ld[7]);
    }
    __syncthreads();   // B1: sBC staged; xs th=1 stores done (th=0 may now overwrite halo)

    // --- xs phase 2: lower half-rows t[0..32), halo from bnd / zeros ---
#pragma unroll
    for (int cc = 0; cc < 2; cc++) {
        const int ch = tid + cc * 256;
        const float w0 = cwp[0*CONVDv + ch], w1 = cwp[1*CONVDv + ch],
                    w2 = cwp[2*CONVDv + ch], w3 = cwp[3*CONVDv + ch];
        float h1 = 0.f, h2 = 0.f, h3 = 0.f;
        if (!atStart) {
            const u16* bp = bnd + ((size_t)(cb - 1) * 3) * 640 + ch;
            h3 = b2f(bp[0]); h2 = b2f(bp[640]); h1 = b2f(bp[1280]);
        }
        conv32_rmw(xrawT + ((size_t)cb * 512 + ch) * 64, w0, w1, w2, w3, cbp[ch], h3, h2, h1);
    }

    // --- B/C conv from LDS: thread = (ch' 0..127, t-half) ---
    u16 o[32];
    {
        const int ch  = tid & 127;
        const int th  = tid >> 7;
        const int t0  = th * 32;
        const int gch = 512 + ch;
        const float w0 = cwp[0*CONVDv + gch], w1 = cwp[1*CONVDv + gch],
                    w2 = cwp[2*CONVDv + gch], w3 = cwp[3*CONVDv + gch];
        const float bias = cbp[gch];
        float h1, h2, h3;
        if (th) {
            h3 = b2f(sBC[29][ch]); h2 = b2f(sBC[30][ch]); h1 = b2f(sBC[31][ch]);
        } else if (!atStart) {
            const u16* bp = bnd + ((size_t)(cb - 1) * 3) * 640 + gch;
            h3 = b2f(bp[0]); h2 = b2f(bp[640]); h1 = b2f(bp[1280]);
        } else { h1 = h2 = h3 = 0.f; }
#pragma unroll
        for (int t = 0; t < 32; t++) {
            const float xv = b2f(sBC[t0 + t][ch]);
            o[t] = f2b(siluf(bias + w0*h3 + w1*h2 + w2*h1 + w3*xv));
            h3 = h2; h2 = h1; h1 = xv;
        }
    }
    __syncthreads();   // B2: all pre-conv LDS reads done
    {
        const int ch = tid & 127, t0 = (tid >> 7) * 32;
#pragma unroll
        for (int t = 0; t < 32; t++) sBC[t0 + t][ch] = o[t];
    }
    __syncthreads();   // B3: conv'd values in LDS
    // --- coalesced writeback: conv'd B/C -> zs rows ---
#pragma unroll
    for (int i = 0; i < 4; i++) {
        const int g = tid + i * 256;
        const int t = g >> 4, s16 = g & 15;
        *(uint4*)(zs + (row0 + t) * ZW + 512 + s16 * 8) = *(const uint4*)(&sBC[t][s16 * 8]);
    }
}

// ---------- K2b: SSD chunk kernel. G=C·B^T; S^T (TMODE, first); Y=M·X (over X) ----------
template<bool TMODE>
__global__ __launch_bounds__(256, 3)
void k2b_ssd(u16* __restrict__ zs, u16* __restrict__ xrawT,
             float* __restrict__ spb, u16* __restrict__ Sbuf,
             const float* __restrict__ Dp)
{
    __shared__ __align__(16) float sG[64][68];     // 17408 B
    __shared__ float sClog[NHEADS][64];            // 2048 B
    __shared__ float sSp[NHEADS][64];
    __shared__ float sWd[NHEADS][64];
    __shared__ __align__(16) u16 sBT[64][72];      // 9216 B (B transposed [n][t])
    const int tid = threadIdx.x;
    const int lane = tid & 63, wave = tid >> 6;
    const int quad = lane >> 4, m16 = lane & 15;
    const int cb = blockIdx.x;
    const size_t row0 = (size_t)cb * 64;

    if (TMODE) {   // B -> sBT transposed
        const int t_ = tid >> 2, ns = (tid & 3) * 16;
        const u16* br = zs + (row0 + t_) * ZW + 512 + ns;
        uint4 a = ((const uint4*)br)[0], b = ((const uint4*)br)[1];
        unsigned uu[8] = {a.x, a.y, a.z, a.w, b.x, b.y, b.z, b.w};
#pragma unroll
        for (int k = 0; k < 8; k++) {
            sBT[ns + 2*k][t_]     = (u16)(uu[k] & 0xffff);
            sBT[ns + 2*k + 1][t_] = (u16)(uu[k] >> 16);
        }
    }

    // --- G = C B^T : wave computes t-rows [16w,16w+16), all 4 s-tiles ---
    {
        const u16* cp = zs + (row0 + 16 * wave + m16) * ZW + 576 + quad * 8;
        bf16x8 cf0 = *(const bf16x8*)(cp);
        bf16x8 cf1 = *(const bf16x8*)(cp + 32);
#pragma unroll
        for (int st = 0; st < 4; st++) {
            const u16* bp = zs + (row0 + 16 * st + m16) * ZW + 512 + quad * 8;
            f32x4 acc = (f32x4){0.f, 0.f, 0.f, 0.f};
            acc = __builtin_amdgcn_mfma_f32_16x16x32_bf16(cf0, *(const bf16x8*)(bp), acc, 0, 0, 0);
            acc = __builtin_amdgcn_mfma_f32_16x16x32_bf16(cf1, *(const bf16x8*)(bp + 32), acc, 0, 0, 0);
#pragma unroll
            for (int i = 0; i < 4; i++)
                sG[16 * wave + quad * 4 + i][16 * st + m16] = acc[i];
        }
    }

    // --- inclusive cumsum of log dA; wave handles heads 2w, 2w+1 (lane = t) ---
#pragma unroll
    for (int hh = 0; hh < 2; hh++) {
        const int h = wave * 2 + hh;
        float c = spb[(row0 + lane) * 24 + 8 + h];
        const float sp = spb[(row0 + lane) * 24 + h];
#pragma unroll
        for (int d = 1; d < 64; d <<= 1) {
            const float o = __shfl_up(c, d, 64);
            if (lane >= d) c += o;
        }
        sClog[h][lane] = c;
        sSp[h][lane] = sp;
        if (TMODE) {
            spb[(row0 + lane) * 24 + 16 + h] = __expf(c);
            const float cl63 = __shfl(c, 63, 64);
            sWd[h][lane] = __expf(cl63 - c) * sp;
        }
    }
    __syncthreads();

    if (TMODE) {
        // --- S phase (before Y overwrites X): S^T[p][n] = sum_t (w_t x_t[p]) B_t[n] ---
        for (int h = 0; h < NHEADS; h++) {
            bf16x8 Ahi[2], Alo[2];
#pragma unroll
            for (int kk = 0; kk < 2; kk++) {
                const u16* xp = xrawT + ((size_t)cb * 512 + h * 64 + 16 * wave + m16) * 64
                                + 32 * kk + quad * 8;
                bf16x8 xf = *(const bf16x8*)xp;
                const float* wp = &sWd[h][32 * kk + quad * 8];
#pragma unroll
                for (int j = 0; j < 8; j++) {
                    const float v = b2f((u16)xf[j]) * wp[j];
                    const u16 hi = f2b(v);
                    Ahi[kk][j] = (short)hi;
                    Alo[kk][j] = (short)f2b(v - b2f(hi));
                }
            }
            u16* sb = Sbuf + ((size_t)cb * 8 + h) * 4096;
#pragma unroll
            for (int nt = 0; nt < 4; nt++) {
                f32x4 acc = (f32x4){0.f, 0.f, 0.f, 0.f};
#pragma unroll
                for (int kk = 0; kk < 2; kk++) {
                    const bf16x8 bf_ = *(const bf16x8*)(&sBT[16 * nt + m16][32 * kk + quad * 8]);
                    acc = __builtin_amdgcn_mfma_f32_16x16x32_bf16(Ahi[kk], bf_, acc, 0, 0, 0);
                    acc = __builtin_amdgcn_mfma_f32_16x16x32_bf16(Alo[kk], bf_, acc, 0, 0, 0);
                }
#pragma unroll
                for (int i = 0; i < 4; i++)
                    sb[(16 * wave + quad * 4 + i) * 64 + 16 * nt + m16] = f2b(acc[i]);
            }
        }
        __syncthreads();   // all X reads (S phase) complete before Y stores
    }

    // --- Y phase: Y = M·X ; TMODE stores Y^T over X in xrawT; band gates into z cols ---
    const int t = 16 * wave + m16;
    for (int h = 0; h < NHEADS; h++) {
        const float Dh = Dp[h];
        const float clt = sClog[h][t];
        bf16x8 Mhi[2], Mlo[2];
#pragma unroll
        for (int kk = 0; kk < 2; kk++) {
            const float* gp = &sG[t][32 * kk + quad * 8];
            const float* cp = &sClog[h][32 * kk + quad * 8];
            const float* pp = &sSp[h][32 * kk + quad * 8];
#pragma unroll
            for (int j = 0; j < 8; j++) {
                const int s = 32 * kk + quad * 8 + j;
                float m = (s <= t) ? (__expf(clt - cp[j]) * pp[j] * gp[j]) : 0.f;
                if (s == t) m += Dh;
                const u16 hi = f2b(m);
                Mhi[kk][j] = (short)hi;
                Mlo[kk][j] = (short)f2b(m - b2f(hi));
            }
        }
        bf16x8 xf[4][2];
#pragma unroll
        for (int pt = 0; pt < 4; pt++)
#pragma unroll
            for (int kk = 0; kk < 2; kk++)
                xf[pt][kk] = *(const bf16x8*)(xrawT
                    + ((size_t)cb * 512 + h * 64 + 16 * pt + m16) * 64 + 32 * kk + quad * 8);
        if (TMODE) __syncthreads();   // all waves loaded head h's X before any store
        f32x4 accY[4];
#pragma unroll
        for (int pt = 0; pt < 4; pt++) {
            accY[pt] = (f32x4){0.f, 0.f, 0.f, 0.f};
#pragma unroll
            for (int kk = 0; kk < 2; kk++) {
                accY[pt] = __builtin_amdgcn_mfma_f32_16x16x32_bf16(Mhi[kk], xf[pt][kk], accY[pt], 0, 0, 0);
                accY[pt] = __builtin_amdgcn_mfma_f32_16x16x32_bf16(Mlo[kk], xf[pt][kk], accY[pt], 0, 0, 0);
            }
        }
#pragma unroll
        for (int pt = 0; pt < 4; pt++) {
            if (TMODE) {   // Y^T[p][t], packed 4 u16 (t = 16w+quad*4+i)
                uint2 v;
                v.x = (unsigned)f2b(accY[pt][0]) | ((unsigned)f2b(accY[pt][1]) << 16);
                v.y = (unsigned)f2b(accY[pt][2]) | ((unsigned)f2b(accY[pt][3]) << 16);
                *(uint2*)(xrawT + ((size_t)cb * 512 + h * 64 + 16 * pt + m16) * 64
                          + 16 * wave + quad * 4) = v;
            } else {       // gate with silu(z), store into z cols (row-major for K3)
#pragma unroll
                for (int i = 0; i < 4; i++) {
                    const size_t row = row0 + 16 * wave + quad * 4 + i;
                    const int col = h * 64 + 16 * pt + m16;
                    const u16 zv = zs[row * ZW + col];
                    zs[row * ZW + col] = f2b(accY[pt][i] * siluf(b2f(zv)));
                }
            }
        }
    }
}

// ---------- K2c: combine chunk states (time pass). In-place S->H. ----------
__global__ __launch_bounds__(64, 4)
void k2c_states(u16* __restrict__ Sbuf, const float* __restrict__ spb)
{
    const int p = threadIdx.x, h = blockIdx.y, s = blockIdx.x;  // s 0..127
    float H[64];
#pragma unroll
    for (int n = 0; n < 64; n++) H[n] = 0.f;
    for (int c = 1; c < 8; c++) {
        const float P = spb[((size_t)s * 512 + (c - 1) * 64 + 63) * 24 + 16 + h];
        u16* sp_ = Sbuf + (((size_t)(s * 8 + c - 1) * 8 + h) * 4096) + p * 64;
#pragma unroll
        for (int n = 0; n < 64; n += 8) {
            uint4 v = *(const uint4*)(sp_ + n);
            unsigned uu[4] = {v.x, v.y, v.z, v.w};
            float sv[8];
#pragma unroll
            for (int w2 = 0; w2 < 4; w2++) { sv[2*w2] = bflo(uu[w2]); sv[2*w2+1] = bfhi(uu[w2]); }
#pragma unroll
            for (int e = 0; e < 8; e++) H[n + e] = fmaf(P, H[n + e], sv[e]);
            uint4 o;
            o.x = (unsigned)f2b(H[n+0]) | ((unsigned)f2b(H[n+1]) << 16);
            o.y = (unsigned)f2b(H[n+2]) | ((unsigned)f2b(H[n+3]) << 16);
            o.z = (unsigned)f2b(H[n+4]) | ((unsigned)f2b(H[n+5]) << 16);
            o.w = (unsigned)f2b(H[n+6]) | ((unsigned)f2b(H[n+7]) << 16);
            *(uint4*)(sp_ + n) = o;
        }
    }
}

// ---------- K2d: Y += diag(a)·C·H, gate with silu(z), write rows into zs z cols ----------
__global__ __launch_bounds__(256, 4)
void k2d_corr(u16* __restrict__ zs, const u16* __restrict__ xrawT,
              const float* __restrict__ spb, const u16* __restrict__ Sbuf)
{
    const int tid = threadIdx.x;
    const int lane = tid & 63, wave = tid >> 6;
    const int quad = lane >> 4, m16 = lane & 15;
    const int cb = blockIdx.x;
    const int c = cb & 7;
    const size_t row0 = (size_t)cb * 64;

    for (int h = 0; h < NHEADS; h++) {
        f32x4 acc[4];
#pragma unroll
        for (int pt = 0; pt < 4; pt++) {   // partial Y from xrawT [p][t]
            const uint2 v = *(const uint2*)(xrawT
                + ((size_t)cb * 512 + h * 64 + 16 * pt + m16) * 64 + 16 * wave + quad * 4);
            acc[pt][0] = bflo(v.x); acc[pt][1] = bfhi(v.x);
            acc[pt][2] = bflo(v.y); acc[pt][3] = bfhi(v.y);
        }
        if (c) {
            const float at = spb[(row0 + 16 * wave + m16) * 24 + 16 + h];
            bf16x8 Ahi[2], Alo[2];
#pragma unroll
            for (int kk = 0; kk < 2; kk++) {
                const u16* cp = zs + (row0 + 16 * wave + m16) * ZW + 576 + 32 * kk + quad * 8;
                bf16x8 cf = *(const bf16x8*)cp;
#pragma unroll
                for (int j = 0; j < 8; j++) {
                    const float v = b2f((u16)cf[j]) * at;
                    const u16 hi = f2b(v);
                    Ahi[kk][j] = (short)hi;
                    Alo[kk][j] = (short)f2b(v - b2f(hi));
                }
            }
            const u16* hb = Sbuf + ((size_t)(cb - 1) * 8 + h) * 4096;
#pragma unroll
            for (int pt = 0; pt < 4; pt++) {
#pragma unroll
                for (int kk = 0; kk < 2; kk++) {
                    bf16x8 hf = *(const bf16x8*)(hb + (16 * pt + m16) * 64 + 32 * kk + quad * 8);
                    acc[pt] = __builtin_amdgcn_mfma_f32_16x16x32_bf16(Ahi[kk], hf, acc[pt], 0, 0, 0);
                    acc[pt] = __builtin_amdgcn_mfma_f32_16x16x32_bf16(Alo[kk], hf, acc[pt], 0, 0, 0);
                }
            }
        }
#pragma unroll
        for (int pt = 0; pt < 4; pt++) {
#pragma unroll
            for (int i = 0; i < 4; i++) {
                const size_t row = row0 + 16 * wave + quad * 4 + i;
                const int col = h * 64 + 16 * pt + m16;
                const u16 zv = zs[row * ZW + col];
                zs[row * ZW + col] = f2b(acc[pt][i] * siluf(b2f(zv)));
            }
        }
    }
}

// ---------- K3: rmsnorm(gated y) @ (gn*Wout) + residual. 64 tok/block, 4 waves, A in regs ----------
// Occupancy-first redesign: no LDS A-staging (each wave rmsnorms its own 16 rows straight
// into fragments; row-sum via shfl_xor over the 4 quads), half-j W stages (16 KB LDS x2),
// per-j f32x4 acc stored immediately. Target 12 waves/CU (3 blocks) vs 7 before.
template<bool TMODE>
__global__ __launch_bounds__(256, 3)
void k3_mfma(const u16* __restrict__ zs, const float* __restrict__ src,
             float* __restrict__ dst,
             const u16* __restrict__ Whi, const u16* __restrict__ Wlo)
{
    __shared__ __align__(16) char smem[32768];   // buf0 = Whi(j) 16KB, buf1 = Wlo(j) 16KB
    const int tid = threadIdx.x;
    const int cb  = blockIdx.x;                  // 1024 blocks, 64 tokens each
    const int R0  = cb * 64;
    const int lane = tid & 63, wave = tid >> 6;  // 4 waves
    const int quad = lane >> 4, m16 = lane & 15;

#define K3_STAGE(hc)                                                              \
    {                                                                             \
        const int jj = (hc) >> 1;                                                 \
        const char* wb = (const char*)((((hc) & 1) ? Wlo : Whi) + (size_t)jj * 8192); \
        char* db = smem + ((hc) & 1) * 16384 + wave * 4096;                       \
        _Pragma("unroll")                                                         \
        for (int i = 0; i < 4; i++)                                               \
            gl_lds16(wb + wave * 4096 + i * 1024 + lane * 16, db + i * 1024);     \
    }

    K3_STAGE(0);   // Whi j=0 in flight while we build A-fragments

    // --- pass 1: sum of squares over this lane's 128 cols (row = wave*16+m16) ---
    const u16* yr = zs + (size_t)(R0 + wave * 16 + m16) * ZW + quad * 8;
    float ss = 0.f;
#pragma unroll
    for (int kk = 0; kk < 16; kk++) {
        uint4 u = *(const uint4*)(yr + kk * 32);
        unsigned uu[4] = {u.x, u.y, u.z, u.w};
#pragma unroll
        for (int w2 = 0; w2 < 4; w2++) {
            const float a = bflo(uu[w2]), b = bfhi(uu[w2]);
            ss += a * a + b * b;
        }
    }
    ss += __shfl_xor(ss, 16, 64);   // reduce across the 4 quads of this row
    ss += __shfl_xor(ss, 32, 64);
    const float rstd = rsqrtf(ss * (1.0f / DINv) + 1e-6f);

    // --- pass 2: reload (L1/L2-hot) and split hi/lo into fragments ---
    bf16x8 ah[16], al[16];
#pragma unroll
    for (int kk = 0; kk < 16; kk++) {
        uint4 u = *(const uint4*)(yr + kk * 32);
        unsigned uu[4] = {u.x, u.y, u.z, u.w};
#pragma unroll
        for (int w2 = 0; w2 < 4; w2++) {
            const float a = bflo(uu[w2]) * rstd;
            const float b = bfhi(uu[w2]) * rstd;
            u16 hi = f2b(a);
            ah[kk][2*w2]   = (short)hi; al[kk][2*w2]   = (short)f2b(a - b2f(hi));
            hi = f2b(b);
            ah[kk][2*w2+1] = (short)hi; al[kk][2*w2+1] = (short)f2b(b - b2f(hi));
        }
    }
    __syncthreads();   // buf0 (Whi j=0) landed

    for (int j = 0; j < 16; j++) {
        K3_STAGE(2 * j + 1);                           // Wlo(j) -> buf1
        f32x4 acc = (f32x4){0.f, 0.f, 0.f, 0.f};
        const u16* tb0 = (const u16*)smem + lane * 8;  // linear in lane
#pragma unroll
        for (int kk = 0; kk < 16; kk++) {
            bf16x8 bh = *(const bf16x8*)(tb0 + kk * 512);
            acc = __builtin_amdgcn_mfma_f32_16x16x32_bf16(ah[kk], bh, acc, 0, 0, 0);
            acc = __builtin_amdgcn_mfma_f32_16x16x32_bf16(al[kk], bh, acc, 0, 0, 0);
        }
        __syncthreads();                               // buf1 ready; buf0 reads done
        if (j < 15) K3_STAGE(2 * j + 2);               // Whi(j+1) -> buf0
        const u16* tb1 = (const u16*)(smem + 16384) + lane * 8;
#pragma unroll
        for (int kk = 0; kk < 16; kk++) {
            bf16x8 bl = *(const bf16x8*)(tb1 + kk * 512);
            acc = __builtin_amdgcn_mfma_f32_16x16x32_bf16(ah[kk], bl, acc, 0, 0, 0);
        }
        { // epilogue for column tile j: +residual, store
            const int col = 16 * j + m16;
#pragma unroll
            for (int i = 0; i < 4; i++) {
                const size_t inrow = (size_t)(R0 + wave * 16 + quad * 4 + i);
                const float v = acc[i] + src[inrow * Hd + col];
                size_t orow;
                if (TMODE) {
                    const size_t sq = inrow >> 9;
                    const size_t tt = inrow & 511;
                    orow = ((sq >> 6) * 512 + tt) * 64 + (sq & 63);
                } else {
                    orow = inrow;
                }
                dst[orow * Hd + col] = v;
            }
        }
        __syncthreads();                               // buf0(j+1) ready; buf1 reads done
    }
#undef K3_STAGE
}

extern "C" void kernel_launch(void* const* d_in, const int* in_sizes, int n_in,
                              void* d_out, int out_size, void* d_ws, size_t ws_size,
                              hipStream_t stream) {
    const float* x      = (const float*)d_in[0];
    const float* t_norm = (const float*)d_in[1];
    const float* t_Win  = (const float*)d_in[2];
    const float* t_cw   = (const float*)d_in[3];
    const float* t_cb   = (const float*)d_in[4];
    const float* t_dtb  = (const float*)d_in[5];
    const float* t_Alog = (const float*)d_in[6];
    const float* t_D    = (const float*)d_in[7];
    const float* t_gn   = (const float*)d_in[8];
    const float* t_Wout = (const float*)d_in[9];
    const float* b_norm = (const float*)d_in[10];
    const float* b_Win  = (const float*)d_in[11];
    const float* b_cw   = (const float*)d_in[12];
    const float* b_cb   = (const float*)d_in[13];
    const float* b_dtb  = (const float*)d_in[14];
    const float* b_Alog = (const float*)d_in[15];
    const float* b_D    = (const float*)d_in[16];
    const float* b_gn   = (const float*)d_in[17];
    const float* b_Wout = (const float*)d_in[18];

    float* out = (float*)d_out;
    char*  wsb = (char*)d_ws;
    float* xbuf = (float*)wsb;
    u16*   Sbuf = (u16*)wsb;                       // overlays xbuf (disjoint lifetimes)
    size_t off = 67108864;
    u16* W1hi = (u16*)(wsb + off); off += (size_t)12 * 74 * 4096 * 2;
    u16* W1lo = (u16*)(wsb + off); off += (size_t)12 * 74 * 4096 * 2;
    u16* W2hi = (u16*)(wsb + off); off += (size_t)12 * 16 * 8192 * 2;
    u16* W2lo = (u16*)(wsb + off); off += (size_t)12 * 16 * 8192 * 2;
    u16* zs   = (u16*)(wsb + off); off += (size_t)NTOK * ZW * 2;
    float* spb = (float*)(wsb + off); off += (size_t)NTOK * 24 * 4;
    u16* xrawT = (u16*)(wsb + off); off += (size_t)NTOK * 512 * 2;
    u16* bnd  = (u16*)(wsb + off);

    kprep_win<<<dim3(74, 12), 512, 0, stream>>>(t_Win, b_Win, W1hi, W1lo);
    kprep_wout<<<dim3(16, 12), 512, 0, stream>>>(t_Wout, t_gn, b_Wout, b_gn, W2hi, W2lo);

    for (int i = 0; i < NLAY; i++) {
        const float* src_t = (i == 0) ? x : out;
        // ---- time pass: 128 seqs x L=512, transposed store ----
        k1_mfma<<<NCH, 512, 0, stream>>>(src_t, zs, xrawT, bnd, t_norm + i * Hd,
                 W1hi + (size_t)i * 74 * 4096, W1lo + (size_t)i * 74 * 4096);
        k2a_conv<<<NCH, 256, 0, stream>>>(zs, xrawT, spb, bnd,
                 t_cw + i * 4 * CONVDv, t_cb + i * CONVDv, t_dtb + i * NHEADS,
                 t_Alog + i * NHEADS, 512);
        k2b_ssd<true><<<NCH, 256, 0, stream>>>(zs, xrawT, spb, Sbuf, t_D + i * NHEADS);
        k2c_states<<<dim3(128, NHEADS), 64, 0, stream>>>(Sbuf, spb);
        k2d_corr<<<NCH, 256, 0, stream>>>(zs, xrawT, spb, Sbuf);
        k3_mfma<true><<<NCH, 256, 0, stream>>>(zs, src_t, xbuf,
                 W2hi + (size_t)i * 16 * 8192, W2lo + (size_t)i * 16 * 8192);
        // ---- band pass: 1024 seqs x L=64 (single chunk), identity store ----
        k1_mfma<<<NCH, 512, 0, stream>>>(xbuf, zs, xrawT, bnd, b_norm + i * Hd,
                 W1hi + (size_t)(i + 6) * 74 * 4096, W1lo + (size_t)(i + 6) * 74 * 4096);
        k2a_conv<<<NCH, 256, 0, stream>>>(zs, xrawT, spb, bnd,
                 b_cw + i * 4 * CONVDv, b_cb + i * CONVDv, b_dtb + i * NHEADS,
                 b_Alog + i * NHEADS, 64);
        k2b_ssd<false><<<NCH, 256, 0, stream>>>(zs, xrawT, spb, Sbuf, b_D + i * NHEADS);
        k3_mfma<false><<<NCH, 256, 0, stream>>>(zs, xbuf, out,
                 W2hi + (size_t)(i + 6) * 16 * 8192, W2lo + (size_t)(i + 6) * 16 * 8192);
    }
}

// Round 4
// 5291.541 us; speedup vs baseline: 1.1935x; 1.1935x over previous
//
#include <hip/hip_runtime.h>
#include <math.h>

#define NLAY   6
#define Hd     256
#define DINv   512
#define NHEADS 8
#define CONVDv 640
#define PROJv  1160   // 2*DIN + 2*N + HEADS
#define ZW     656    // zsmall row: z 512 | B 64 | C 64 | dt 8 | pad 8
#define NTOK   65536
#define NCH    1024   // 64-token chunks

typedef __attribute__((ext_vector_type(8))) short bf16x8;
typedef __attribute__((ext_vector_type(4))) float f32x4;
typedef unsigned short u16;

__device__ __forceinline__ float siluf(float v) {
    // fast silu: v * rcp(1 + exp(-v)); result is bf16-rounded downstream.
    return v * __builtin_amdgcn_rcpf(1.0f + __expf(-v));
}
__device__ __forceinline__ float bflo(unsigned u) { return __uint_as_float(u << 16); }
__device__ __forceinline__ float bfhi(unsigned u) { return __uint_as_float(u & 0xffff0000u); }
__device__ __forceinline__ u16 f2b(float f) {  // RNE fp32->bf16
    unsigned u = __float_as_uint(f);
    return (u16)((u + 0x7fffu + ((u >> 16) & 1u)) >> 16);
}
__device__ __forceinline__ float b2f(u16 s) { return __uint_as_float(((unsigned)s) << 16); }

__device__ __forceinline__ void gl_lds16(const void* g, void* l) {
    __builtin_amdgcn_global_load_lds((const __attribute__((address_space(1))) unsigned int*)g,
                                     (__attribute__((address_space(3))) unsigned int*)l, 16, 0, 0);
}

// ---------- prep: Win -> bf16 hi/lo, fragment order [li][j(74)][kk(8)][quad(4)][col(16)][e(8)] ----------
// [quad][col] order => a wave's ds_read_b128 of one kk-block is byte-linear in lane
// (lane*16) => conflict-free.
__global__ __launch_bounds__(512)
void kprep_win(const float* __restrict__ tW, const float* __restrict__ bW,
               u16* __restrict__ Whi, u16* __restrict__ Wlo)
{
    const int li = blockIdx.y, j = blockIdx.x;    // j 0..73
    const int t  = threadIdx.x;
    const int kk = t >> 6, col = (t >> 2) & 15, quad = t & 3;
    const float* W = (li < 6) ? (tW + (size_t)li * Hd * PROJv)
                              : (bW + (size_t)(li - 6) * Hd * PROJv);
    const int fullcol = 16 * j + col;
    const size_t ob = ((size_t)li * 74 + j) * 4096 + kk * 512 + quad * 128 + col * 8;
#pragma unroll
    for (int e = 0; e < 8; e++) {
        const int k = kk * 32 + quad * 8 + e;
        const float v = (fullcol < PROJv) ? W[(size_t)k * PROJv + fullcol] : 0.f;
        const u16 hi = f2b(v);
        Whi[ob + e] = hi;
        Wlo[ob + e] = f2b(v - b2f(hi));
    }
}

// ---------- prep: Wout*gn -> bf16 hi/lo, fragment order [li][j(16)][kk(16)][quad(4)][col(16)][e(8)] ----------
__global__ __launch_bounds__(512)
void kprep_wout(const float* __restrict__ tW, const float* __restrict__ tg,
                const float* __restrict__ bW, const float* __restrict__ bg,
                u16* __restrict__ Whi, u16* __restrict__ Wlo)
{
    const int li = blockIdx.y, j = blockIdx.x;    // j 0..15
    const int t  = threadIdx.x;
    const int kk = t >> 5, col = (t >> 1) & 15, qh = t & 1;
    const float* W = (li < 6) ? tW + (size_t)li * DINv * Hd : bW + (size_t)(li - 6) * DINv * Hd;
    const float* g = (li < 6) ? tg + li * DINv : bg + (li - 6) * DINv;
    const int fullcol = 16 * j + col;
#pragma unroll
    for (int q = 0; q < 2; q++) {
        const int quad = qh * 2 + q;
        const size_t ob = ((size_t)li * 16 + j) * 8192 + kk * 512 + quad * 128 + col * 8;
#pragma unroll
        for (int e = 0; e < 8; e++) {
            const int k = kk * 32 + quad * 8 + e;
            const float v = W[(size_t)k * Hd + fullcol] * g[k];
            const u16 hi = f2b(v);
            Whi[ob + e] = hi;
            Wlo[ob + e] = f2b(v - b2f(hi));
        }
    }
}

// ---------- K1: rmsnorm(x) @ Win. z/B/C/dt -> zs rows; xs -> xrawT[p][t]; halo dup -> bnd ----------
__global__ __launch_bounds__(512, 4)
void k1_mfma(const float* __restrict__ src, u16* __restrict__ zs,
             u16* __restrict__ xrawT, u16* __restrict__ bnd,
             const float* __restrict__ nw,
             const u16* __restrict__ Whi, const u16* __restrict__ Wlo)
{
    __shared__ __align__(16) char smem[67584];    // union: sA (66KB) then sW dbuf (64KB)
    u16* sAh = (u16*)smem;                        // 64*264
    u16* sAl = sAh + 64 * 264;
    const int tid = threadIdx.x;
    const int cb  = blockIdx.x;
    const int R0  = cb * 64;

    { // phase A: load 64x256 fp32, rmsnorm, hi/lo -> LDS
        const int tok = tid >> 3, l8 = tid & 7;
        const float* xr = src + ((size_t)(R0 + tok)) * Hd + l8 * 32;
        float vv[32];
#pragma unroll
        for (int q = 0; q < 8; q++) {
            float4 v = ((const float4*)xr)[q];
            vv[4*q] = v.x; vv[4*q+1] = v.y; vv[4*q+2] = v.z; vv[4*q+3] = v.w;
        }
        float ss = 0.f;
#pragma unroll
        for (int j = 0; j < 32; j++) ss += vv[j] * vv[j];
#pragma unroll
        for (int m = 4; m >= 1; m >>= 1) ss += __shfl_xor(ss, m, 8);
        const float rstd = rsqrtf(ss * (1.0f / Hd) + 1e-6f);
        const float* nr = nw + l8 * 32;
        u16* dh = sAh + tok * 264 + l8 * 32;
        u16* dl = sAl + tok * 264 + l8 * 32;
#pragma unroll
        for (int j = 0; j < 32; j++) {
            const float val = vv[j] * rstd * nr[j];
            const u16 hi = f2b(val);
            dh[j] = hi;
            dl[j] = f2b(val - b2f(hi));
        }
    }
    __syncthreads();

    const int lane = tid & 63, wave = tid >> 6;
    const int rh = wave >> 1, cw = wave & 1;
    const int quad = lane >> 4, m16 = lane & 15;

    bf16x8 ah[8], al[8];
    {
        const u16* ph = sAh + (rh * 16 + m16) * 264 + quad * 8;
        const u16* pl = sAl + (rh * 16 + m16) * 264 + quad * 8;
#pragma unroll
        for (int kk = 0; kk < 8; kk++) {
            ah[kk] = *(const bf16x8*)(ph + kk * 32);
            al[kk] = *(const bf16x8*)(pl + kk * 32);
        }
    }
    __syncthreads();   // all frag reads done before sW overlays sA

    u16* sW = (u16*)smem;  // 2 bufs x 16384 u16

#define K1_STAGE(p, buf)                                                          \
    {                                                                             \
        const int obase = wave * 4096;                                            \
        _Pragma("unroll")                                                         \
        for (int i = 0; i < 4; i++) {                                             \
            const int o = obase + i * 1024;                                       \
            const int chunk = o >> 13, t2 = chunk >> 1, hl = chunk & 1;           \
            const int within = o & 8191;                                          \
            const u16* sbase = (hl ? Wlo : Whi) + (size_t)(2 * (p) + t2) * 4096;  \
            gl_lds16((const char*)sbase + within + lane * 16,                     \
                     (char*)sW + (buf) * 32768 + o);                              \
        }                                                                         \
    }

    K1_STAGE(0, 0);
    __syncthreads();

    for (int p = 0; p < 37; p++) {
        if (p < 36) K1_STAGE(p + 1, (p + 1) & 1);
        const int j = 2 * p + cw;
        const u16* tb = sW + (p & 1) * 16384 + cw * 8192 + lane * 8;   // linear in lane
        f32x4 acc = (f32x4){0.f, 0.f, 0.f, 0.f};
#pragma unroll
        for (int kk = 0; kk < 8; kk++) {
            bf16x8 bh = *(const bf16x8*)(tb + kk * 512);
            bf16x8 bl = *(const bf16x8*)(tb + 4096 + kk * 512);
            acc = __builtin_amdgcn_mfma_f32_16x16x32_bf16(ah[kk], bh, acc, 0, 0, 0);
            acc = __builtin_amdgcn_mfma_f32_16x16x32_bf16(al[kk], bh, acc, 0, 0, 0);
            acc = __builtin_amdgcn_mfma_f32_16x16x32_bf16(ah[kk], bl, acc, 0, 0, 0);
        }
        const int fullcol = 16 * j + m16;
        if (j < 32) {                         // z columns
            u16* zr = zs + (size_t)(R0 + rh * 16 + quad * 4) * ZW + fullcol;
#pragma unroll
            for (int i = 0; i < 4; i++) zr[(size_t)i * ZW] = f2b(acc[i]);
        } else if (j < 64) {                  // xs -> xrawT [ch][t], packed 4 u16
            const int ch = fullcol - 512;
            uint2 v;
            v.x = (unsigned)f2b(acc[0]) | ((unsigned)f2b(acc[1]) << 16);
            v.y = (unsigned)f2b(acc[2]) | ((unsigned)f2b(acc[3]) << 16);
            *(uint2*)(xrawT + ((size_t)cb * 512 + ch) * 64 + rh * 16 + quad * 4) = v;
            if (rh == 3 && quad == 3) {       // rows 61..63 halo dup
#pragma unroll
                for (int i = 1; i < 4; i++)
                    bnd[((size_t)cb * 3 + (i - 1)) * 640 + ch] = f2b(acc[i]);
            }
        } else if (j < 73) {                  // B/C/dt columns (zs col = fullcol-512)
            const int zc = fullcol - 512;
            u16* zr = zs + (size_t)(R0 + rh * 16 + quad * 4) * ZW + zc;
#pragma unroll
            for (int i = 0; i < 4; i++) zr[(size_t)i * ZW] = f2b(acc[i]);
            if (j < 72 && rh == 3 && quad == 3) {
#pragma unroll
                for (int i = 1; i < 4; i++)
                    bnd[((size_t)cb * 3 + (i - 1)) * 640 + zc] = f2b(acc[i]);
            }
        }
        __syncthreads();
    }
#undef K1_STAGE
}

// ---------- K2a: conv4+silu (FIR -> fully t-parallel) + softplus/logdA ----------
__device__ __forceinline__ void conv32_rmw(u16* xp, float w0, float w1, float w2, float w3,
                                           float bias, float h3, float h2, float h1)
{
    uint4 va = ((const uint4*)xp)[0], vb = ((const uint4*)xp)[1],
          vc = ((const uint4*)xp)[2], vd = ((const uint4*)xp)[3];
    unsigned uu[16] = {va.x, va.y, va.z, va.w, vb.x, vb.y, vb.z, vb.w,
                       vc.x, vc.y, vc.z, vc.w, vd.x, vd.y, vd.z, vd.w};
    unsigned ou[16];
#pragma unroll
    for (int k = 0; k < 16; k++) {
        const float x0 = bflo(uu[k]);
        const u16 o0 = f2b(siluf(bias + w0*h3 + w1*h2 + w2*h1 + w3*x0));
        h3 = h2; h2 = h1; h1 = x0;
        const float x1 = bfhi(uu[k]);
        const u16 o1 = f2b(siluf(bias + w0*h3 + w1*h2 + w2*h1 + w3*x1));
        h3 = h2; h2 = h1; h1 = x1;
        ou[k] = (unsigned)o0 | ((unsigned)o1 << 16);
    }
    ((uint4*)xp)[0] = make_uint4(ou[0],  ou[1],  ou[2],  ou[3]);
    ((uint4*)xp)[1] = make_uint4(ou[4],  ou[5],  ou[6],  ou[7]);
    ((uint4*)xp)[2] = make_uint4(ou[8],  ou[9],  ou[10], ou[11]);
    ((uint4*)xp)[3] = make_uint4(ou[12], ou[13], ou[14], ou[15]);
}

__global__ __launch_bounds__(256, 4)
void k2a_conv(u16* __restrict__ zs, u16* __restrict__ xrawT,
              float* __restrict__ spb, const u16* __restrict__ bnd,
              const float* __restrict__ cwp, const float* __restrict__ cbp,
              const float* __restrict__ dtbp, const float* __restrict__ alogp, int L)
{
    __shared__ __align__(16) u16 sBC[64][128];   // 16 KB: pre-conv B/C, [t][ch']
    const int tid = threadIdx.x;
    const int cb  = blockIdx.x;
    const size_t row0 = (size_t)cb * 64;
    const bool atStart = (((int)(row0 % (size_t)L)) == 0);
    const int lane = tid & 63, wave = tid >> 6;

    // --- issue async stage of pre-conv B/C (zs cols 512..639) -> LDS ---
#pragma unroll
    for (int j = 0; j < 4; j++) {
        const int t0 = wave * 16 + j * 4;        // wave-uniform LDS dest; per-lane src
        gl_lds16(zs + (row0 + t0 + (lane >> 4)) * ZW + 512 + (lane & 15) * 8,
                 (char*)sBC + t0 * 256);
    }

    // --- xs phase 1: upper half-rows t[32..64), halo x[29..31] read pre-conv ---
#pragma unroll
    for (int cc = 0; cc < 2; cc++) {
        const int ch = tid + cc * 256;
        const float w0 = cwp[0*CONVDv + ch], w1 = cwp[1*CONVDv + ch],
                    w2 = cwp[2*CONVDv + ch], w3 = cwp[3*CONVDv + ch];
        u16* xp = xrawT + ((size_t)cb * 512 + ch) * 64 + 32;
        const uint2 hv = *(const uint2*)(xp - 4);          // x[28..31]
        conv32_rmw(xp, w0, w1, w2, w3, cbp[ch], bfhi(hv.x), bflo(hv.y), bfhi(hv.y));
    }

    // --- dt: pointwise softplus + log dA, one token-row per thread ---
    if (tid < 64) {
        const int t = tid;
        const uint4 dv = *(const uint4*)(zs + (row0 + t) * ZW + 640);   // heads 0..7
        const unsigned uu[4] = {dv.x, dv.y, dv.z, dv.w};
        float sp[8], ld[8];
#pragma unroll
        for (int h = 0; h < 8; h++) {
            const float d = ((h & 1) ? bfhi(uu[h >> 1]) : bflo(uu[h >> 1])) + dtbp[h];
            const float s = (d > 20.f) ? d : __logf(1.f + __expf(d));
            sp[h] = s;
            ld[h] = -__expf(alogp[h]) * s;
        }
        float* ob = spb + (row0 + t) * 24;
        *(float4*)(ob)      = make_float4(sp[0], sp[1], sp[2], sp[3]);
        *(float4*)(ob + 4)  = make_float4(sp[4], sp[5], sp[6], sp[7]);
        *(float4*)(ob + 8)  = make_float4(ld[0], ld[1], ld[2], ld[3]);
        *(float4*)(ob + 12) = make_float4(ld[4], ld[5], ld[6], ld[7]);
    }
    __syncthreads();   // B1: sBC staged; xs th=1 stores done (th=0 may now overwrite halo)

    // --- xs phase 2: lower half-rows t[0..32), halo from bnd / zeros ---
#pragma unroll
    for (int cc = 0; cc < 2; cc++) {
        const int ch = tid + cc * 256;
        const float w0 = cwp[0*CONVDv + ch], w1 = cwp[1*CONVDv + ch],
                    w2 = cwp[2*CONVDv + ch], w3 = cwp[3*CONVDv + ch];
        float h1 = 0.f, h2 = 0.f, h3 = 0.f;
        if (!atStart) {
            const u16* bp = bnd + ((size_t)(cb - 1) * 3) * 640 + ch;
            h3 = b2f(bp[0]); h2 = b2f(bp[640]); h1 = b2f(bp[1280]);
        }
        conv32_rmw(xrawT + ((size_t)cb * 512 + ch) * 64, w0, w1, w2, w3, cbp[ch], h3, h2, h1);
    }

    // --- B/C conv from LDS: thread = (ch' 0..127, t-half) ---
    u16 o[32];
    {
        const int ch  = tid & 127;
        const int th  = tid >> 7;
        const int t0  = th * 32;
        const int gch = 512 + ch;
        const float w0 = cwp[0*CONVDv + gch], w1 = cwp[1*CONVDv + gch],
                    w2 = cwp[2*CONVDv + gch], w3 = cwp[3*CONVDv + gch];
        const float bias = cbp[gch];
        float h1, h2, h3;
        if (th) {
            h3 = b2f(sBC[29][ch]); h2 = b2f(sBC[30][ch]); h1 = b2f(sBC[31][ch]);
        } else if (!atStart) {
            const u16* bp = bnd + ((size_t)(cb - 1) * 3) * 640 + gch;
            h3 = b2f(bp[0]); h2 = b2f(bp[640]); h1 = b2f(bp[1280]);
        } else { h1 = h2 = h3 = 0.f; }
#pragma unroll
        for (int t = 0; t < 32; t++) {
            const float xv = b2f(sBC[t0 + t][ch]);
            o[t] = f2b(siluf(bias + w0*h3 + w1*h2 + w2*h1 + w3*xv));
            h3 = h2; h2 = h1; h1 = xv;
        }
    }
    __syncthreads();   // B2: all pre-conv LDS reads done
    {
        const int ch = tid & 127, t0 = (tid >> 7) * 32;
#pragma unroll
        for (int t = 0; t < 32; t++) sBC[t0 + t][ch] = o[t];
    }
    __syncthreads();   // B3: conv'd values in LDS
    // --- coalesced writeback: conv'd B/C -> zs rows ---
#pragma unroll
    for (int i = 0; i < 4; i++) {
        const int g = tid + i * 256;
        const int t = g >> 4, s16 = g & 15;
        *(uint4*)(zs + (row0 + t) * ZW + 512 + s16 * 8) = *(const uint4*)(&sBC[t][s16 * 8]);
    }
}

// ---------- K2b: SSD chunk kernel. G=C·B^T; S^T (TMODE, first); Y=M·X (over X) ----------
template<bool TMODE>
__global__ __launch_bounds__(256, 3)
void k2b_ssd(u16* __restrict__ zs, u16* __restrict__ xrawT,
             float* __restrict__ spb, u16* __restrict__ Sbuf,
             const float* __restrict__ Dp)
{
    __shared__ __align__(16) float sG[64][68];     // 17408 B
    __shared__ float sClog[NHEADS][64];            // 2048 B
    __shared__ float sSp[NHEADS][64];
    __shared__ float sWd[NHEADS][64];
    __shared__ __align__(16) u16 sBT[64][72];      // 9216 B (B transposed [n][t])
    const int tid = threadIdx.x;
    const int lane = tid & 63, wave = tid >> 6;
    const int quad = lane >> 4, m16 = lane & 15;
    const int cb = blockIdx.x;
    const size_t row0 = (size_t)cb * 64;

    if (TMODE) {   // B -> sBT transposed
        const int t_ = tid >> 2, ns = (tid & 3) * 16;
        const u16* br = zs + (row0 + t_) * ZW + 512 + ns;
        uint4 a = ((const uint4*)br)[0], b = ((const uint4*)br)[1];
        unsigned uu[8] = {a.x, a.y, a.z, a.w, b.x, b.y, b.z, b.w};
#pragma unroll
        for (int k = 0; k < 8; k++) {
            sBT[ns + 2*k][t_]     = (u16)(uu[k] & 0xffff);
            sBT[ns + 2*k + 1][t_] = (u16)(uu[k] >> 16);
        }
    }

    // --- G = C B^T : wave computes t-rows [16w,16w+16), all 4 s-tiles ---
    {
        const u16* cp = zs + (row0 + 16 * wave + m16) * ZW + 576 + quad * 8;
        bf16x8 cf0 = *(const bf16x8*)(cp);
        bf16x8 cf1 = *(const bf16x8*)(cp + 32);
#pragma unroll
        for (int st = 0; st < 4; st++) {
            const u16* bp = zs + (row0 + 16 * st + m16) * ZW + 512 + quad * 8;
            f32x4 acc = (f32x4){0.f, 0.f, 0.f, 0.f};
            acc = __builtin_amdgcn_mfma_f32_16x16x32_bf16(cf0, *(const bf16x8*)(bp), acc, 0, 0, 0);
            acc = __builtin_amdgcn_mfma_f32_16x16x32_bf16(cf1, *(const bf16x8*)(bp + 32), acc, 0, 0, 0);
#pragma unroll
            for (int i = 0; i < 4; i++)
                sG[16 * wave + quad * 4 + i][16 * st + m16] = acc[i];
        }
    }

    // --- inclusive cumsum of log dA; wave handles heads 2w, 2w+1 (lane = t) ---
#pragma unroll
    for (int hh = 0; hh < 2; hh++) {
        const int h = wave * 2 + hh;
        float c = spb[(row0 + lane) * 24 + 8 + h];
        const float sp = spb[(row0 + lane) * 24 + h];
#pragma unroll
        for (int d = 1; d < 64; d <<= 1) {
            const float o = __shfl_up(c, d, 64);
            if (lane >= d) c += o;
        }
        sClog[h][lane] = c;
        sSp[h][lane] = sp;
        if (TMODE) {
            spb[(row0 + lane) * 24 + 16 + h] = __expf(c);
            const float cl63 = __shfl(c, 63, 64);
            sWd[h][lane] = __expf(cl63 - c) * sp;
        }
    }
    __syncthreads();

    if (TMODE) {
        // --- S phase (before Y overwrites X): S^T[p][n] = sum_t (w_t x_t[p]) B_t[n] ---
        for (int h = 0; h < NHEADS; h++) {
            bf16x8 Ahi[2], Alo[2];
#pragma unroll
            for (int kk = 0; kk < 2; kk++) {
                const u16* xp = xrawT + ((size_t)cb * 512 + h * 64 + 16 * wave + m16) * 64
                                + 32 * kk + quad * 8;
                bf16x8 xf = *(const bf16x8*)xp;
                const float* wp = &sWd[h][32 * kk + quad * 8];
#pragma unroll
                for (int j = 0; j < 8; j++) {
                    const float v = b2f((u16)xf[j]) * wp[j];
                    const u16 hi = f2b(v);
                    Ahi[kk][j] = (short)hi;
                    Alo[kk][j] = (short)f2b(v - b2f(hi));
                }
            }
            u16* sb = Sbuf + ((size_t)cb * 8 + h) * 4096;
#pragma unroll
            for (int nt = 0; nt < 4; nt++) {
                f32x4 acc = (f32x4){0.f, 0.f, 0.f, 0.f};
#pragma unroll
                for (int kk = 0; kk < 2; kk++) {
                    const bf16x8 bf_ = *(const bf16x8*)(&sBT[16 * nt + m16][32 * kk + quad * 8]);
                    acc = __builtin_amdgcn_mfma_f32_16x16x32_bf16(Ahi[kk], bf_, acc, 0, 0, 0);
                    acc = __builtin_amdgcn_mfma_f32_16x16x32_bf16(Alo[kk], bf_, acc, 0, 0, 0);
                }
#pragma unroll
                for (int i = 0; i < 4; i++)
                    sb[(16 * wave + quad * 4 + i) * 64 + 16 * nt + m16] = f2b(acc[i]);
            }
        }
        __syncthreads();   // all X reads (S phase) complete before Y stores
    }

    // --- Y phase: Y = M·X ; TMODE stores Y^T over X in xrawT; band gates into z cols ---
    const int t = 16 * wave + m16;
    for (int h = 0; h < NHEADS; h++) {
        const float Dh = Dp[h];
        const float clt = sClog[h][t];
        bf16x8 Mhi[2], Mlo[2];
#pragma unroll
        for (int kk = 0; kk < 2; kk++) {
            const float* gp = &sG[t][32 * kk + quad * 8];
            const float* cp = &sClog[h][32 * kk + quad * 8];
            const float* pp = &sSp[h][32 * kk + quad * 8];
#pragma unroll
            for (int j = 0; j < 8; j++) {
                const int s = 32 * kk + quad * 8 + j;
                float m = (s <= t) ? (__expf(clt - cp[j]) * pp[j] * gp[j]) : 0.f;
                if (s == t) m += Dh;
                const u16 hi = f2b(m);
                Mhi[kk][j] = (short)hi;
                Mlo[kk][j] = (short)f2b(m - b2f(hi));
            }
        }
        bf16x8 xf[4][2];
#pragma unroll
        for (int pt = 0; pt < 4; pt++)
#pragma unroll
            for (int kk = 0; kk < 2; kk++)
                xf[pt][kk] = *(const bf16x8*)(xrawT
                    + ((size_t)cb * 512 + h * 64 + 16 * pt + m16) * 64 + 32 * kk + quad * 8);
        if (TMODE) __syncthreads();   // all waves loaded head h's X before any store
        f32x4 accY[4];
#pragma unroll
        for (int pt = 0; pt < 4; pt++) {
            accY[pt] = (f32x4){0.f, 0.f, 0.f, 0.f};
#pragma unroll
            for (int kk = 0; kk < 2; kk++) {
                accY[pt] = __builtin_amdgcn_mfma_f32_16x16x32_bf16(Mhi[kk], xf[pt][kk], accY[pt], 0, 0, 0);
                accY[pt] = __builtin_amdgcn_mfma_f32_16x16x32_bf16(Mlo[kk], xf[pt][kk], accY[pt], 0, 0, 0);
            }
        }
#pragma unroll
        for (int pt = 0; pt < 4; pt++) {
            if (TMODE) {   // Y^T[p][t], packed 4 u16 (t = 16w+quad*4+i)
                uint2 v;
                v.x = (unsigned)f2b(accY[pt][0]) | ((unsigned)f2b(accY[pt][1]) << 16);
                v.y = (unsigned)f2b(accY[pt][2]) | ((unsigned)f2b(accY[pt][3]) << 16);
                *(uint2*)(xrawT + ((size_t)cb * 512 + h * 64 + 16 * pt + m16) * 64
                          + 16 * wave + quad * 4) = v;
            } else {       // gate with silu(z), store into z cols (row-major for K3)
#pragma unroll
                for (int i = 0; i < 4; i++) {
                    const size_t row = row0 + 16 * wave + quad * 4 + i;
                    const int col = h * 64 + 16 * pt + m16;
                    const u16 zv = zs[row * ZW + col];
                    zs[row * ZW + col] = f2b(accY[pt][i] * siluf(b2f(zv)));
                }
            }
        }
    }
}

// ---------- K2c: combine chunk states (time pass). In-place S->H. ----------
__global__ __launch_bounds__(64, 4)
void k2c_states(u16* __restrict__ Sbuf, const float* __restrict__ spb)
{
    const int p = threadIdx.x, h = blockIdx.y, s = blockIdx.x;  // s 0..127
    float H[64];
#pragma unroll
    for (int n = 0; n < 64; n++) H[n] = 0.f;
    for (int c = 1; c < 8; c++) {
        const float P = spb[((size_t)s * 512 + (c - 1) * 64 + 63) * 24 + 16 + h];
        u16* sp_ = Sbuf + (((size_t)(s * 8 + c - 1) * 8 + h) * 4096) + p * 64;
#pragma unroll
        for (int n = 0; n < 64; n += 8) {
            uint4 v = *(const uint4*)(sp_ + n);
            unsigned uu[4] = {v.x, v.y, v.z, v.w};
            float sv[8];
#pragma unroll
            for (int w2 = 0; w2 < 4; w2++) { sv[2*w2] = bflo(uu[w2]); sv[2*w2+1] = bfhi(uu[w2]); }
#pragma unroll
            for (int e = 0; e < 8; e++) H[n + e] = fmaf(P, H[n + e], sv[e]);
            uint4 o;
            o.x = (unsigned)f2b(H[n+0]) | ((unsigned)f2b(H[n+1]) << 16);
            o.y = (unsigned)f2b(H[n+2]) | ((unsigned)f2b(H[n+3]) << 16);
            o.z = (unsigned)f2b(H[n+4]) | ((unsigned)f2b(H[n+5]) << 16);
            o.w = (unsigned)f2b(H[n+6]) | ((unsigned)f2b(H[n+7]) << 16);
            *(uint4*)(sp_ + n) = o;
        }
    }
}

// ---------- K2d: Y += diag(a)·C·H, gate with silu(z), write rows into zs z cols ----------
__global__ __launch_bounds__(256, 4)
void k2d_corr(u16* __restrict__ zs, const u16* __restrict__ xrawT,
              const float* __restrict__ spb, const u16* __restrict__ Sbuf)
{
    const int tid = threadIdx.x;
    const int lane = tid & 63, wave = tid >> 6;
    const int quad = lane >> 4, m16 = lane & 15;
    const int cb = blockIdx.x;
    const int c = cb & 7;
    const size_t row0 = (size_t)cb * 64;

    for (int h = 0; h < NHEADS; h++) {
        f32x4 acc[4];
#pragma unroll
        for (int pt = 0; pt < 4; pt++) {   // partial Y from xrawT [p][t]
            const uint2 v = *(const uint2*)(xrawT
                + ((size_t)cb * 512 + h * 64 + 16 * pt + m16) * 64 + 16 * wave + quad * 4);
            acc[pt][0] = bflo(v.x); acc[pt][1] = bfhi(v.x);
            acc[pt][2] = bflo(v.y); acc[pt][3] = bfhi(v.y);
        }
        if (c) {
            const float at = spb[(row0 + 16 * wave + m16) * 24 + 16 + h];
            bf16x8 Ahi[2], Alo[2];
#pragma unroll
            for (int kk = 0; kk < 2; kk++) {
                const u16* cp = zs + (row0 + 16 * wave + m16) * ZW + 576 + 32 * kk + quad * 8;
                bf16x8 cf = *(const bf16x8*)cp;
#pragma unroll
                for (int j = 0; j < 8; j++) {
                    const float v = b2f((u16)cf[j]) * at;
                    const u16 hi = f2b(v);
                    Ahi[kk][j] = (short)hi;
                    Alo[kk][j] = (short)f2b(v - b2f(hi));
                }
            }
            const u16* hb = Sbuf + ((size_t)(cb - 1) * 8 + h) * 4096;
#pragma unroll
            for (int pt = 0; pt < 4; pt++) {
#pragma unroll
                for (int kk = 0; kk < 2; kk++) {
                    bf16x8 hf = *(const bf16x8*)(hb + (16 * pt + m16) * 64 + 32 * kk + quad * 8);
                    acc[pt] = __builtin_amdgcn_mfma_f32_16x16x32_bf16(Ahi[kk], hf, acc[pt], 0, 0, 0);
                    acc[pt] = __builtin_amdgcn_mfma_f32_16x16x32_bf16(Alo[kk], hf, acc[pt], 0, 0, 0);
                }
            }
        }
#pragma unroll
        for (int pt = 0; pt < 4; pt++) {
#pragma unroll
            for (int i = 0; i < 4; i++) {
                const size_t row = row0 + 16 * wave + quad * 4 + i;
                const int col = h * 64 + 16 * pt + m16;
                const u16 zv = zs[row * ZW + col];
                zs[row * ZW + col] = f2b(acc[pt][i] * siluf(b2f(zv)));
            }
        }
    }
}

// ---------- K3: rmsnorm(gated y) @ (gn*Wout) + residual. 64 tok/block, 4 waves, A in regs ----------
// r3 structure, r4 fix: __launch_bounds__(256,2) so the ~150-reg live set (ah[16]+al[16]
// fragments + acc) is NOT spilled (r3's (256,3) bound forced 84 VGPRs + 134 MB of scratch
// traffic). Natural occupancy ~3 waves/SIMD from actual usage.
template<bool TMODE>
__global__ __launch_bounds__(256, 2)
void k3_mfma(const u16* __restrict__ zs, const float* __restrict__ src,
             float* __restrict__ dst,
             const u16* __restrict__ Whi, const u16* __restrict__ Wlo)
{
    __shared__ __align__(16) char smem[32768];   // buf0 = Whi(j) 16KB, buf1 = Wlo(j) 16KB
    const int tid = threadIdx.x;
    const int cb  = blockIdx.x;                  // 1024 blocks, 64 tokens each
    const int R0  = cb * 64;
    const int lane = tid & 63, wave = tid >> 6;  // 4 waves
    const int quad = lane >> 4, m16 = lane & 15;

#define K3_STAGE(hc)                                                              \
    {                                                                             \
        const int jj = (hc) >> 1;                                                 \
        const char* wb = (const char*)((((hc) & 1) ? Wlo : Whi) + (size_t)jj * 8192); \
        char* db = smem + ((hc) & 1) * 16384 + wave * 4096;                       \
        _Pragma("unroll")                                                         \
        for (int i = 0; i < 4; i++)                                               \
            gl_lds16(wb + wave * 4096 + i * 1024 + lane * 16, db + i * 1024);     \
    }

    K3_STAGE(0);   // Whi j=0 in flight while we build A-fragments

    // --- pass 1: sum of squares over this lane's 128 cols (row = wave*16+m16) ---
    const u16* yr = zs + (size_t)(R0 + wave * 16 + m16) * ZW + quad * 8;
    float ss = 0.f;
#pragma unroll
    for (int kk = 0; kk < 16; kk++) {
        uint4 u = *(const uint4*)(yr + kk * 32);
        float a;
        a = bflo(u.x); ss += a * a;  a = bfhi(u.x); ss += a * a;
        a = bflo(u.y); ss += a * a;  a = bfhi(u.y); ss += a * a;
        a = bflo(u.z); ss += a * a;  a = bfhi(u.z); ss += a * a;
        a = bflo(u.w); ss += a * a;  a = bfhi(u.w); ss += a * a;
    }
    ss += __shfl_xor(ss, 16, 64);   // reduce across the 4 quads of this row
    ss += __shfl_xor(ss, 32, 64);
    const float rstd = rsqrtf(ss * (1.0f / DINv) + 1e-6f);

    // --- pass 2: reload (L1/L2-hot) and split hi/lo into fragments ---
    bf16x8 ah[16], al[16];
#pragma unroll
    for (int kk = 0; kk < 16; kk++) {
        uint4 u = *(const uint4*)(yr + kk * 32);
        unsigned w0 = u.x, w1 = u.y, w2 = u.z, w3 = u.w;
        float a, b;
        u16 hi;
        a = bflo(w0) * rstd; b = bfhi(w0) * rstd;
        hi = f2b(a); ah[kk][0] = (short)hi; al[kk][0] = (short)f2b(a - b2f(hi));
        hi = f2b(b); ah[kk][1] = (short)hi; al[kk][1] = (short)f2b(b - b2f(hi));
        a = bflo(w1) * rstd; b = bfhi(w1) * rstd;
        hi = f2b(a); ah[kk][2] = (short)hi; al[kk][2] = (short)f2b(a - b2f(hi));
        hi = f2b(b); ah[kk][3] = (short)hi; al[kk][3] = (short)f2b(b - b2f(hi));
        a = bflo(w2) * rstd; b = bfhi(w2) * rstd;
        hi = f2b(a); ah[kk][4] = (short)hi; al[kk][4] = (short)f2b(a - b2f(hi));
        hi = f2b(b); ah[kk][5] = (short)hi; al[kk][5] = (short)f2b(b - b2f(hi));
        a = bflo(w3) * rstd; b = bfhi(w3) * rstd;
        hi = f2b(a); ah[kk][6] = (short)hi; al[kk][6] = (short)f2b(a - b2f(hi));
        hi = f2b(b); ah[kk][7] = (short)hi; al[kk][7] = (short)f2b(b - b2f(hi));
    }
    __syncthreads();   // buf0 (Whi j=0) landed

    for (int j = 0; j < 16; j++) {
        K3_STAGE(2 * j + 1);                           // Wlo(j) -> buf1
        f32x4 acc = (f32x4){0.f, 0.f, 0.f, 0.f};
        const u16* tb0 = (const u16*)smem + lane * 8;  // linear in lane
#pragma unroll
        for (int kk = 0; kk < 16; kk++) {
            bf16x8 bh = *(const bf16x8*)(tb0 + kk * 512);
            acc = __builtin_amdgcn_mfma_f32_16x16x32_bf16(ah[kk], bh, acc, 0, 0, 0);
            acc = __builtin_amdgcn_mfma_f32_16x16x32_bf16(al[kk], bh, acc, 0, 0, 0);
        }
        __syncthreads();                               // buf1 ready; buf0 reads done
        if (j < 15) K3_STAGE(2 * j + 2);               // Whi(j+1) -> buf0
        const u16* tb1 = (const u16*)(smem + 16384) + lane * 8;
#pragma unroll
        for (int kk = 0; kk < 16; kk++) {
            bf16x8 bl = *(const bf16x8*)(tb1 + kk * 512);
            acc = __builtin_amdgcn_mfma_f32_16x16x32_bf16(ah[kk], bl, acc, 0, 0, 0);
        }
        { // epilogue for column tile j: +residual, store
            const int col = 16 * j + m16;
#pragma unroll
            for (int i = 0; i < 4; i++) {
                const size_t inrow = (size_t)(R0 + wave * 16 + quad * 4 + i);
                const float v = acc[i] + src[inrow * Hd + col];
                size_t orow;
                if (TMODE) {
                    const size_t sq = inrow >> 9;
                    const size_t tt = inrow & 511;
                    orow = ((sq >> 6) * 512 + tt) * 64 + (sq & 63);
                } else {
                    orow = inrow;
                }
                dst[orow * Hd + col] = v;
            }
        }
        __syncthreads();                               // buf0(j+1) ready; buf1 reads done
    }
#undef K3_STAGE
}

extern "C" void kernel_launch(void* const* d_in, const int* in_sizes, int n_in,
                              void* d_out, int out_size, void* d_ws, size_t ws_size,
                              hipStream_t stream) {
    const float* x      = (const float*)d_in[0];
    const float* t_norm = (const float*)d_in[1];
    const float* t_Win  = (const float*)d_in[2];
    const float* t_cw   = (const float*)d_in[3];
    const float* t_cb   = (const float*)d_in[4];
    const float* t_dtb  = (const float*)d_in[5];
    const float* t_Alog = (const float*)d_in[6];
    const float* t_D    = (const float*)d_in[7];
    const float* t_gn   = (const float*)d_in[8];
    const float* t_Wout = (const float*)d_in[9];
    const float* b_norm = (const float*)d_in[10];
    const float* b_Win  = (const float*)d_in[11];
    const float* b_cw   = (const float*)d_in[12];
    const float* b_cb   = (const float*)d_in[13];
    const float* b_dtb  = (const float*)d_in[14];
    const float* b_Alog = (const float*)d_in[15];
    const float* b_D    = (const float*)d_in[16];
    const float* b_gn   = (const float*)d_in[17];
    const float* b_Wout = (const float*)d_in[18];

    float* out = (float*)d_out;
    char*  wsb = (char*)d_ws;
    float* xbuf = (float*)wsb;
    u16*   Sbuf = (u16*)wsb;                       // overlays xbuf (disjoint lifetimes)
    size_t off = 67108864;
    u16* W1hi = (u16*)(wsb + off); off += (size_t)12 * 74 * 4096 * 2;
    u16* W1lo = (u16*)(wsb + off); off += (size_t)12 * 74 * 4096 * 2;
    u16* W2hi = (u16*)(wsb + off); off += (size_t)12 * 16 * 8192 * 2;
    u16* W2lo = (u16*)(wsb + off); off += (size_t)12 * 16 * 8192 * 2;
    u16* zs   = (u16*)(wsb + off); off += (size_t)NTOK * ZW * 2;
    float* spb = (float*)(wsb + off); off += (size_t)NTOK * 24 * 4;
    u16* xrawT = (u16*)(wsb + off); off += (size_t)NTOK * 512 * 2;
    u16* bnd  = (u16*)(wsb + off);

    kprep_win<<<dim3(74, 12), 512, 0, stream>>>(t_Win, b_Win, W1hi, W1lo);
    kprep_wout<<<dim3(16, 12), 512, 0, stream>>>(t_Wout, t_gn, b_Wout, b_gn, W2hi, W2lo);

    for (int i = 0; i < NLAY; i++) {
        const float* src_t = (i == 0) ? x : out;
        // ---- time pass: 128 seqs x L=512, transposed store ----
        k1_mfma<<<NCH, 512, 0, stream>>>(src_t, zs, xrawT, bnd, t_norm + i * Hd,
                 W1hi + (size_t)i * 74 * 4096, W1lo + (size_t)i * 74 * 4096);
        k2a_conv<<<NCH, 256, 0, stream>>>(zs, xrawT, spb, bnd,
                 t_cw + i * 4 * CONVDv, t_cb + i * CONVDv, t_dtb + i * NHEADS,
                 t_Alog + i * NHEADS, 512);
        k2b_ssd<true><<<NCH, 256, 0, stream>>>(zs, xrawT, spb, Sbuf, t_D + i * NHEADS);
        k2c_states<<<dim3(128, NHEADS), 64, 0, stream>>>(Sbuf, spb);
        k2d_corr<<<NCH, 256, 0, stream>>>(zs, xrawT, spb, Sbuf);
        k3_mfma<true><<<NCH, 256, 0, stream>>>(zs, src_t, xbuf,
                 W2hi + (size_t)i * 16 * 8192, W2lo + (size_t)i * 16 * 8192);
        // ---- band pass: 1024 seqs x L=64 (single chunk), identity store ----
        k1_mfma<<<NCH, 512, 0, stream>>>(xbuf, zs, xrawT, bnd, b_norm + i * Hd,
                 W1hi + (size_t)(i + 6) * 74 * 4096, W1lo + (size_t)(i + 6) * 74 * 4096);
        k2a_conv<<<NCH, 256, 0, stream>>>(zs, xrawT, spb, bnd,
                 b_cw + i * 4 * CONVDv, b_cb + i * CONVDv, b_dtb + i * NHEADS,
                 b_Alog + i * NHEADS, 64);
        k2b_ssd<false><<<NCH, 256, 0, stream>>>(zs, xrawT, spb, Sbuf, b_D + i * NHEADS);
        k3_mfma<false><<<NCH, 256, 0, stream>>>(zs, xbuf, out,
                 W2hi + (size_t)(i + 6) * 16 * 8192, W2lo + (size_t)(i + 6) * 16 * 8192);
    }
}